// Round 2
// baseline (729.746 us; speedup 1.0000x reference)
//
#include <hip/hip_runtime.h>
#include <stdint.h>

#define N_IDS     1000000
#define ZCH       400000
#define EMB_DIM   128
#define TOTAL     (2 * N_IDS)
#define HASH_SZ   4000000            // id values are in [0, 4M)
#define BLOCK     256
#define GRID      ((TOTAL + BLOCK - 1) / BLOCK)   // 7813
#define OVF       (ZCH - 1)
#define NBASE     16384              // ceil(4M / 256) = 15625, padded
#define NCHUNK    (HASH_SZ / 16)     // 250000 16-byte LUT chunks per feature

// rem(id) = searchsorted(mch, id) is MONOTONE in id. Within a 256-id block,
// slot = base[id>>8] + delta, delta = #mch entries in [blockstart, id)
// ~ Poisson(25.6), max ~56 -> fits u8; 0xFF = miss sentinel.
//
// Build is ONE kernel: each thread owns one 16-byte LUT chunk, does one
// binary search for its 256-block base (16 consecutive lanes share the
// identical search path -> cache-hot, non-divergent), walks the block's
// entries, and emits sentinel+deltas as one aligned 16 B store. No separate
// init pass, no ordering dependency, no per-entry scatter.
//
// Finalize is folded into remap_loss via fence + atomic-counter last-block
// reduction (double accumulation in the SAME index order as the old
// finalize kernel -> bit-identical loss).
//
// d_out (float32): [0] = loss, [1 .. 2M] = remapped indices as floats.
// d_ws: [lut8_0: 4M u8][lut8_1: 4M u8][base0: 16K int][base1: 16K int]
//       [partials: GRID floats][counter: uint]   (~8.2 MB)

__global__ __launch_bounds__(256) void build_kernel(
    const int* __restrict__ mch0, const int* __restrict__ mch1,
    unsigned char* __restrict__ lut0, unsigned char* __restrict__ lut1,
    int* __restrict__ base0, int* __restrict__ base1,
    unsigned int* __restrict__ counter)
{
    const int t = blockIdx.x * 256 + threadIdx.x;
    if (t == 0) *counter = 0u;               // reset last-block counter (ws poisoned)
    if (t >= 2 * NCHUNK) return;

    const int feat  = t >= NCHUNK;
    const int c     = feat ? (t - NCHUNK) : t;
    const int* __restrict__ mch = feat ? mch1 : mch0;

    const int vbase  = c << 4;               // chunk start id
    const int bstart = vbase & ~255;         // 256-id block start

    // block base slot = lower_bound(mch, bstart); identical path for the
    // 16 lanes sharing a block -> L1-hot, minimal divergence
    int lo = 0, hi = ZCH;
    while (lo < hi) {
        int mid = (lo + hi) >> 1;
        if (mch[mid] < bstart) lo = mid + 1; else hi = mid;
    }
    if ((c & 15) == 0) (feat ? base1 : base0)[c >> 4] = lo;

    // compose 16 bytes in two u64 registers (no runtime-indexed local array)
    unsigned long long w0 = ~0ull, w1 = ~0ull;
    const int vend = vbase + 16;
    int s = lo;
    int prev = (lo > 0) ? mch[lo - 1] : -1;  // < bstart, so never aliases
    while (s < ZCH) {
        const int v = mch[s];
        if (v >= vend) break;
        if (v >= vbase && v != prev) {       // first occurrence owns the slot
            const unsigned long long d = (unsigned long long)(s - lo);
            const int p = v - vbase;
            if (p < 8) { const int sh = p * 8;
                w0 = (w0 & ~(0xFFull << sh)) | (d << sh); }
            else       { const int sh = (p - 8) * 8;
                w1 = (w1 & ~(0xFFull << sh)) | (d << sh); }
        }
        prev = v;
        ++s;
    }
    unsigned long long* dst =
        (unsigned long long*)((feat ? lut1 : lut0) + vbase);
    dst[0] = w0;
    dst[1] = w1;
}

__global__ __launch_bounds__(BLOCK) void remap_loss_kernel(
    const int* __restrict__ ids0, const int* __restrict__ ids1,
    const float* __restrict__ emb0, const float* __restrict__ emb1,
    const unsigned char* __restrict__ lut0, const unsigned char* __restrict__ lut1,
    const int* __restrict__ base0, const int* __restrict__ base1,
    float* __restrict__ out,
    float* __restrict__ partials,
    unsigned int* __restrict__ counter)
{
    const int gid  = blockIdx.x * BLOCK + threadIdx.x;
    const int lane = threadIdx.x & 63;
    const int wave = threadIdx.x >> 6;

    float accl = 0.0f;

    // Wave-uniform activity/feature: TOTAL % 64 == 0 and N_IDS % 64 == 0.
    const bool active = (gid < TOTAL);
    if (active) {
        const int feat = gid >= N_IDS;
        const int i    = feat ? (gid - N_IDS) : gid;
        const int id   = (feat ? ids1 : ids0)[i];
        const float* __restrict__ emb = feat ? emb1 : emb0;

        // the whole "search": one u8 gather (8 MB, L2-resident) + hot base read
        const unsigned int w = (feat ? lut1 : lut0)[id];
        const int          b = (feat ? base1 : base0)[id >> 8];
        const int rem = (w == 0xFFu) ? OVF : (b + (int)w);

        out[1 + gid] = (float)rem;                  // exact: rem < 2^24

        // ---- loss ----
        // ~90.5% of ids hit the overflow row: dedupe it (L1-hot).
        const unsigned long long ovf = __ballot(rem == OVF);
        const int novf = __popcll(ovf);
        if (novf) {
            const float2* __restrict__ row =
                (const float2*)(emb + (size_t)OVF * EMB_DIM);
            float2 v = row[lane];                   // 64 x 8 B = one row
            float s = v.x + v.y;
            #pragma unroll
            for (int o = 32; o > 0; o >>= 1)
                s += __shfl_xor(s, o, 64);
            if (lane == 0) accl += (float)novf * s;
        }

        // Remaining ~6 distinct rows per wave: 2 rows/iteration,
        // half-wave x float4 (32 x 16 B = 512 B = one row).
        const int half = lane >> 5;
        const int l32  = lane & 31;
        unsigned long long hits = ~ovf;             // all 64 lanes are valid
        #pragma unroll 1
        while (hits) {                              // wave-uniform mask
            int j0 = __ffsll(hits) - 1;
            hits &= hits - 1;
            const bool dup = (hits == 0);           // odd count: duplicate j0
            int j1 = dup ? j0 : (__ffsll(hits) - 1);
            if (!dup) hits &= hits - 1;
            int r = __shfl(rem, half ? j1 : j0, 64);
            const float4* __restrict__ row =
                (const float4*)(emb + (size_t)r * EMB_DIM);
            float4 v = row[l32];
            float s4 = (v.x + v.y) + (v.z + v.w);
            accl += (half && dup) ? 0.0f : s4;      // drop the duplicated half
        }
    }

    // wave reduction (64 lanes)
    #pragma unroll
    for (int o = 32; o > 0; o >>= 1)
        accl += __shfl_down(accl, o, 64);

    __shared__ float wsum[BLOCK / 64];
    if (lane == 0) wsum[wave] = accl;
    __syncthreads();
    if (threadIdx.x == 0) {
        float s = 0.0f;
        #pragma unroll
        for (int w = 0; w < BLOCK / 64; ++w) s += wsum[w];
        partials[blockIdx.x] = s;
    }

    // ---- fused finalize: last block to arrive reduces the partials ----
    __shared__ bool amLast;
    if (threadIdx.x == 0) {
        __threadfence();                            // release partials (agent scope)
        amLast = (atomicAdd(counter, 1u) == (unsigned)(GRID - 1));
    }
    __syncthreads();
    if (amLast) {
        __threadfence();                            // acquire others' partials
        __shared__ double sh[BLOCK];
        double sd = 0.0;
        for (int i = threadIdx.x; i < GRID; i += BLOCK)   // same index order as
            sd += (double)partials[i];                    // the old finalize
        sh[threadIdx.x] = sd;
        __syncthreads();
        #pragma unroll
        for (int stride = BLOCK / 2; stride > 0; stride >>= 1) {
            if (threadIdx.x < stride) sh[threadIdx.x] += sh[threadIdx.x + stride];
            __syncthreads();
        }
        if (threadIdx.x == 0)
            out[0] = (float)(sh[0] / ((double)TOTAL * (double)EMB_DIM));
    }
}

extern "C" void kernel_launch(void* const* d_in, const int* in_sizes, int n_in,
                              void* d_out, int out_size, void* d_ws, size_t ws_size,
                              hipStream_t stream) {
    const int*   ids0 = (const int*)d_in[0];
    const int*   ids1 = (const int*)d_in[1];
    const int*   mch0 = (const int*)d_in[2];
    const int*   mch1 = (const int*)d_in[3];
    const float* emb0 = (const float*)d_in[4];
    const float* emb1 = (const float*)d_in[5];

    float* out = (float*)d_out;
    unsigned char* lut0 = (unsigned char*)d_ws;
    unsigned char* lut1 = lut0 + HASH_SZ;
    int*   base0    = (int*)(lut1 + HASH_SZ);
    int*   base1    = base0 + NBASE;
    float* partials = (float*)(base1 + NBASE);
    unsigned int* counter = (unsigned int*)(partials + GRID);

    build_kernel<<<(2 * NCHUNK + 255) / 256, 256, 0, stream>>>(
        mch0, mch1, lut0, lut1, base0, base1, counter);
    remap_loss_kernel<<<GRID, BLOCK, 0, stream>>>(
        ids0, ids1, emb0, emb1, lut0, lut1, base0, base1, out, partials, counter);
}

// Round 3
// 396.313 us; speedup vs baseline: 1.8413x; 1.8413x over previous
//
#include <hip/hip_runtime.h>
#include <stdint.h>

#define N_IDS     1000000
#define ZCH       400000
#define EMB_DIM   128
#define TOTAL     (2 * N_IDS)
#define HASH_SZ   4000000            // id values are in [0, 4M)
#define BLOCK     256
#define GRID      ((TOTAL + BLOCK - 1) / BLOCK)   // 7813
#define OVF       (ZCH - 1)
#define NBASE     16384              // ceil(4M / 256) = 15625, padded
#define NCHUNK    (HASH_SZ / 16)     // 250000 16-byte LUT chunks per feature

// rem(id) = searchsorted(mch, id) is MONOTONE in id. Within a 256-id block,
// slot = base[id>>8] + delta, delta = #mch entries in [blockstart, id)
// ~ Poisson(25.6), max ~56 -> fits u8; 0xFF = miss sentinel.
//
// Build is ONE kernel (verified in R2, absmax 0.0): each thread owns one
// 16-byte LUT chunk, one binary search for its 256-block base (16
// consecutive lanes share the identical search path -> L1-hot), walks the
// block's entries, emits sentinel+deltas as one aligned 16 B store. No
// separate init pass, no per-entry scatter.
//
// R2 lesson: do NOT fuse finalize via per-block __threadfence — device-scope
// release fences writeback/invalidate per-XCD L2 and cost ~370 us across
// 7813 blocks (remap went 406 us latency-bound, 290 GB/s). Separate
// finalize launch is ~3 us. Keep it.
//
// d_out (float32): [0] = loss, [1 .. 2M] = remapped indices as floats.
// d_ws: [lut8_0: 4M u8][lut8_1: 4M u8][base0: 16K int][base1: 16K int]
//       [partials: GRID floats]   (~8.2 MB)

__global__ __launch_bounds__(256) void build_kernel(
    const int* __restrict__ mch0, const int* __restrict__ mch1,
    unsigned char* __restrict__ lut0, unsigned char* __restrict__ lut1,
    int* __restrict__ base0, int* __restrict__ base1)
{
    const int t = blockIdx.x * 256 + threadIdx.x;
    if (t >= 2 * NCHUNK) return;

    const int feat  = t >= NCHUNK;
    const int c     = feat ? (t - NCHUNK) : t;
    const int* __restrict__ mch = feat ? mch1 : mch0;

    const int vbase  = c << 4;               // chunk start id
    const int bstart = vbase & ~255;         // 256-id block start

    // block base slot = lower_bound(mch, bstart)
    int lo = 0, hi = ZCH;
    while (lo < hi) {
        int mid = (lo + hi) >> 1;
        if (mch[mid] < bstart) lo = mid + 1; else hi = mid;
    }
    if ((c & 15) == 0) (feat ? base1 : base0)[c >> 4] = lo;

    // compose 16 bytes in two u64 registers (no runtime-indexed local array)
    unsigned long long w0 = ~0ull, w1 = ~0ull;
    const int vend = vbase + 16;
    int s = lo;
    int prev = (lo > 0) ? mch[lo - 1] : -1;  // < bstart, so never aliases
    while (s < ZCH) {
        const int v = mch[s];
        if (v >= vend) break;
        if (v >= vbase && v != prev) {       // first occurrence owns the slot
            const unsigned long long d = (unsigned long long)(s - lo);
            const int p = v - vbase;
            if (p < 8) { const int sh = p * 8;
                w0 = (w0 & ~(0xFFull << sh)) | (d << sh); }
            else       { const int sh = (p - 8) * 8;
                w1 = (w1 & ~(0xFFull << sh)) | (d << sh); }
        }
        prev = v;
        ++s;
    }
    unsigned long long* dst =
        (unsigned long long*)((feat ? lut1 : lut0) + vbase);
    dst[0] = w0;
    dst[1] = w1;
}

__global__ __launch_bounds__(BLOCK) void remap_loss_kernel(
    const int* __restrict__ ids0, const int* __restrict__ ids1,
    const float* __restrict__ emb0, const float* __restrict__ emb1,
    const unsigned char* __restrict__ lut0, const unsigned char* __restrict__ lut1,
    const int* __restrict__ base0, const int* __restrict__ base1,
    float* __restrict__ out,
    float* __restrict__ partials)
{
    const int gid  = blockIdx.x * BLOCK + threadIdx.x;
    const int lane = threadIdx.x & 63;
    const int wave = threadIdx.x >> 6;

    float accl = 0.0f;

    // Wave-uniform activity/feature: TOTAL % 64 == 0 and N_IDS % 64 == 0.
    const bool active = (gid < TOTAL);
    if (active) {
        const int feat = gid >= N_IDS;
        const int i    = feat ? (gid - N_IDS) : gid;
        const int id   = (feat ? ids1 : ids0)[i];
        const float* __restrict__ emb = feat ? emb1 : emb0;

        // the whole "search": one u8 gather (8 MB, L2-resident) + hot base read
        const unsigned int w = (feat ? lut1 : lut0)[id];
        const int          b = (feat ? base1 : base0)[id >> 8];
        const int rem = (w == 0xFFu) ? OVF : (b + (int)w);

        out[1 + gid] = (float)rem;                  // exact: rem < 2^24

        // ---- loss ----
        // ~90.5% of ids hit the overflow row: dedupe it (L1-hot).
        const unsigned long long ovf = __ballot(rem == OVF);
        const int novf = __popcll(ovf);
        if (novf) {
            const float2* __restrict__ row =
                (const float2*)(emb + (size_t)OVF * EMB_DIM);
            float2 v = row[lane];                   // 64 x 8 B = one row
            float s = v.x + v.y;
            #pragma unroll
            for (int o = 32; o > 0; o >>= 1)
                s += __shfl_xor(s, o, 64);
            if (lane == 0) accl += (float)novf * s;
        }

        // Remaining ~6 distinct rows per wave: 2 rows/iteration,
        // half-wave x float4 (32 x 16 B = 512 B = one row).
        const int half = lane >> 5;
        const int l32  = lane & 31;
        unsigned long long hits = ~ovf;             // all 64 lanes are valid
        #pragma unroll 1
        while (hits) {                              // wave-uniform mask
            int j0 = __ffsll(hits) - 1;
            hits &= hits - 1;
            const bool dup = (hits == 0);           // odd count: duplicate j0
            int j1 = dup ? j0 : (__ffsll(hits) - 1);
            if (!dup) hits &= hits - 1;
            int r = __shfl(rem, half ? j1 : j0, 64);
            const float4* __restrict__ row =
                (const float4*)(emb + (size_t)r * EMB_DIM);
            float4 v = row[l32];
            float s4 = (v.x + v.y) + (v.z + v.w);
            accl += (half && dup) ? 0.0f : s4;      // drop the duplicated half
        }
    }

    // wave reduction (64 lanes)
    #pragma unroll
    for (int o = 32; o > 0; o >>= 1)
        accl += __shfl_down(accl, o, 64);

    __shared__ float wsum[BLOCK / 64];
    if (lane == 0) wsum[wave] = accl;
    __syncthreads();
    if (threadIdx.x == 0) {
        float s = 0.0f;
        #pragma unroll
        for (int w = 0; w < BLOCK / 64; ++w) s += wsum[w];
        partials[blockIdx.x] = s;
    }
}

__global__ __launch_bounds__(256) void finalize_kernel(
    const float* __restrict__ partials, float* __restrict__ out)
{
    __shared__ double sh[256];
    double s = 0.0;
    for (int i = threadIdx.x; i < GRID; i += 256)
        s += (double)partials[i];
    sh[threadIdx.x] = s;
    __syncthreads();
    #pragma unroll
    for (int stride = 128; stride > 0; stride >>= 1) {
        if (threadIdx.x < stride) sh[threadIdx.x] += sh[threadIdx.x + stride];
        __syncthreads();
    }
    if (threadIdx.x == 0)
        out[0] = (float)(sh[0] / ((double)TOTAL * (double)EMB_DIM));
}

extern "C" void kernel_launch(void* const* d_in, const int* in_sizes, int n_in,
                              void* d_out, int out_size, void* d_ws, size_t ws_size,
                              hipStream_t stream) {
    const int*   ids0 = (const int*)d_in[0];
    const int*   ids1 = (const int*)d_in[1];
    const int*   mch0 = (const int*)d_in[2];
    const int*   mch1 = (const int*)d_in[3];
    const float* emb0 = (const float*)d_in[4];
    const float* emb1 = (const float*)d_in[5];

    float* out = (float*)d_out;
    unsigned char* lut0 = (unsigned char*)d_ws;
    unsigned char* lut1 = lut0 + HASH_SZ;
    int*   base0    = (int*)(lut1 + HASH_SZ);
    int*   base1    = base0 + NBASE;
    float* partials = (float*)(base1 + NBASE);

    build_kernel<<<(2 * NCHUNK + 255) / 256, 256, 0, stream>>>(
        mch0, mch1, lut0, lut1, base0, base1);
    remap_loss_kernel<<<GRID, BLOCK, 0, stream>>>(
        ids0, ids1, emb0, emb1, lut0, lut1, base0, base1, out, partials);
    finalize_kernel<<<1, 256, 0, stream>>>(partials, out);
}